// Round 1
// baseline (573.908 us; speedup 1.0000x reference)
//
#include <hip/hip_runtime.h>
#include <hip/hip_bf16.h>

// GroupedEmbeddingBag: T=8 tables [V=100000, D=128] fp32, B=4096 bags/table.
// out[b, t*D+d] = sum_{i in [offs[t][b], offs[t][b+1])} tables[t][values[t][i]][d] * psw[t][i]
//
// R1: latency-bound fix. One WAVE per bag (4 bags / 256-thread block).
//  - lane = (half = row parity, c4 = float4 col block): each row gather is
//    32 lanes x 16B = 512B contiguous; one wave-load covers 2 rows.
//  - 8 rows (4 pair-loads) in flight per wave, indices/weights software-
//    pipelined one group ahead -> gathers never stall on index fetch.
//  - halves combined with shfl_xor(32); lanes 0-31 store float4 (512B/bag).
// R2: identical resubmit — previous session measured 572.1 us; this round's
//     bench failed at the container level (no counters). Re-anchoring baseline.

namespace {
constexpr int T = 8;
constexpr int V = 100000;
constexpr int D = 128;
constexpr int B = 4096;
constexpr int N = 204800;
}

__global__ __launch_bounds__(256) void grouped_ebag_kernel(
    const float* __restrict__ tables,   // [T, V, D]
    const int* __restrict__ values,     // [T, N]
    const int* __restrict__ offsets,    // [T, B+1]
    const float* __restrict__ psw,      // [T, N]
    float* __restrict__ out)            // [B, T*D]
{
    const int wave = threadIdx.x >> 6;            // 0..3
    const int lane = threadIdx.x & 63;
    const int bag  = (blockIdx.x << 2) + wave;    // 0 .. T*B-1, (t, b) ordered
    const int t = bag >> 12;                      // B = 4096
    const int b = bag & (B - 1);
    const int half = lane >> 5;                   // row parity within a pair
    const int c4   = lane & 31;                   // float4 column block

    const int start = offsets[t * (B + 1) + b];
    const int end   = offsets[t * (B + 1) + b + 1];

    const float* __restrict__ tab  = tables + (size_t)t * (V * D);
    const int*   __restrict__ vals = values + (size_t)t * N;
    const float* __restrict__ wgt  = psw    + (size_t)t * N;

    float4 acc = make_float4(0.f, 0.f, 0.f, 0.f);

    const int len  = end - start;
    const int ngrp = len >> 3;                    // groups of 8 rows

    // Software pipeline: indices/weights for group g+1 load while group g gathers.
    int   v[4];
    float wv[4];
    if (ngrp > 0) {
#pragma unroll
        for (int j = 0; j < 4; ++j) {
            v[j]  = vals[start + 2 * j + half];
            wv[j] = wgt [start + 2 * j + half];
        }
    }

    int i = start;
    for (int g = 0; g < ngrp; ++g) {
        int   vn[4] = {0, 0, 0, 0};
        float wn[4] = {0.f, 0.f, 0.f, 0.f};
        const int inext = i + 8;
        if (g + 1 < ngrp) {
#pragma unroll
            for (int j = 0; j < 4; ++j) {
                vn[j] = vals[inext + 2 * j + half];
                wn[j] = wgt [inext + 2 * j + half];
            }
        }
#pragma unroll
        for (int j = 0; j < 4; ++j) {
            const float4 e = *(const float4*)(tab + (size_t)v[j] * D + c4 * 4);
            acc.x = fmaf(e.x, wv[j], acc.x);
            acc.y = fmaf(e.y, wv[j], acc.y);
            acc.z = fmaf(e.z, wv[j], acc.z);
            acc.w = fmaf(e.w, wv[j], acc.w);
        }
#pragma unroll
        for (int j = 0; j < 4; ++j) { v[j] = vn[j]; wv[j] = wn[j]; }
        i = inext;
    }

    // Remainder: pairs of rows (both halves active).
    for (; i + 2 <= end; i += 2) {
        const int   vv = vals[i + half];
        const float ww = wgt [i + half];
        const float4 e = *(const float4*)(tab + (size_t)vv * D + c4 * 4);
        acc.x = fmaf(e.x, ww, acc.x);
        acc.y = fmaf(e.y, ww, acc.y);
        acc.z = fmaf(e.z, ww, acc.z);
        acc.w = fmaf(e.w, ww, acc.w);
    }
    // Last odd row: lanes 0-31 only.
    if (i < end && half == 0) {
        const int   vv = vals[i];
        const float ww = wgt [i];
        const float4 e = *(const float4*)(tab + (size_t)vv * D + c4 * 4);
        acc.x = fmaf(e.x, ww, acc.x);
        acc.y = fmaf(e.y, ww, acc.y);
        acc.z = fmaf(e.z, ww, acc.z);
        acc.w = fmaf(e.w, ww, acc.w);
    }

    // Combine even/odd row halves across the wave.
    acc.x += __shfl_xor(acc.x, 32);
    acc.y += __shfl_xor(acc.y, 32);
    acc.z += __shfl_xor(acc.z, 32);
    acc.w += __shfl_xor(acc.w, 32);

    if (half == 0) {
        *(float4*)(out + (size_t)b * (T * D) + t * D + c4 * 4) = acc;
    }
}

extern "C" void kernel_launch(void* const* d_in, const int* in_sizes, int n_in,
                              void* d_out, int out_size, void* d_ws, size_t ws_size,
                              hipStream_t stream) {
    const float* tables  = (const float*)d_in[0];
    const int*   values  = (const int*)d_in[1];
    const int*   offsets = (const int*)d_in[2];
    const float* psw     = (const float*)d_in[3];
    float*       out     = (float*)d_out;

    dim3 grid((T * B) / 4);   // 4 bags (waves) per 256-thread block
    dim3 block(256);
    grouped_ebag_kernel<<<grid, block, 0, stream>>>(tables, values, offsets, psw, out);
}

// Round 3
// 565.817 us; speedup vs baseline: 1.0143x; 1.0143x over previous
//
#include <hip/hip_runtime.h>

// GroupedEmbeddingBag: T=8 tables [V=100000, D=128] fp32, B=4096 bags/table.
// out[b, t*D+d] = sum_{i in [offs[t][b], offs[t][b+1])} tables[t][values[t][i]][d] * psw[t][i]
//
// R3: scalar-index + sustained-MLP redesign (theory: latency/MLP-bound at
// 1.5 TB/s effective, 24% of HBM — nowhere near a BW wall).
//  - One WAVE per bag. One ROW per wave-load: float2/lane x 64 lanes = 512B
//    contiguous, SCALAR base (global_load_dwordx2 saddr form) -> ~0 VALU
//    address math per row.
//  - Indices/weights for 64 rows fetched with ONE coalesced vector load each,
//    then hoisted to SGPRs via readlane (wave-uniform by construction).
//  - 8-row groups, double-buffered: group g+1's gathers issue BEFORE the
//    vmcnt wait on group g -> 8 rows (4 KB) sustained in flight per wave,
//    never draining to zero (the old kernel drained vmcnt every group).
//  - Tail rows padded with weight 0 (pad loads clamp to a valid row; same
//    address -> cache hit, no extra HBM traffic).
//  - Full row per wave -> no cross-lane reduction; store float2 directly.
// R4: identical resubmit — Round 2 bench failed at the container level
//     (same infra error as Round 0, which also hit a known-good kernel).
//     Audit found no hang/fault vector in R3. Re-running for the measurement.

namespace {
constexpr int T = 8;
constexpr int V = 100000;
constexpr int D = 128;
constexpr int B = 4096;
constexpr int N = 204800;
}

__device__ __forceinline__ float readlane_f(float v, int l) {
    return __int_as_float(__builtin_amdgcn_readlane(__float_as_int(v), l));
}

__global__ __launch_bounds__(256) void grouped_ebag_kernel(
    const float* __restrict__ tables,   // [T, V, D]
    const int* __restrict__ values,     // [T, N]
    const int* __restrict__ offsets,    // [T, B+1]
    const float* __restrict__ psw,      // [T, N]
    float* __restrict__ out)            // [B, T*D]
{
    const int wave = threadIdx.x >> 6;            // 0..3
    const int lane = threadIdx.x & 63;
    const int bag  = (blockIdx.x << 2) + wave;    // (t, b) ordered
    const int t = bag >> 12;                      // B = 4096
    const int b = bag & (B - 1);

    int start = offsets[t * (B + 1) + b];
    int end   = offsets[t * (B + 1) + b + 1];
    start = __builtin_amdgcn_readfirstlane(start);
    end   = __builtin_amdgcn_readfirstlane(end);
    const int len = end - start;

    const float* __restrict__ tab  = tables + (size_t)t * (V * D);
    const int*   __restrict__ vals = values + (size_t)t * N + start;
    const float* __restrict__ wgt  = psw    + (size_t)t * N + start;

    float2 acc = make_float2(0.f, 0.f);

    for (int base = 0; base < len; base += 64) {
        const int rem = len - base;
        const int m   = rem < 64 ? rem : 64;      // rows in this chunk (1..64)

        // One coalesced vector load of up to 64 indices + 64 weights.
        const int pos  = base + lane;
        const int posc = pos < len ? pos : (len - 1);   // clamp: stay in-bag
        const int   vidx = vals[posc];
        const float vw   = (pos < len) ? wgt[posc] : 0.f;  // pad rows weigh 0

        const int ngrp = (m + 7) >> 3;            // 8-row groups, <= 8

        float2 bufA[8], bufB[8];                  // static-indexed only

        auto LOAD = [&](float2 (&buf)[8], int g) {
#pragma unroll
            for (int j = 0; j < 8; ++j) {
                const int r   = (g << 3) + j;                    // uniform
                const int row = __builtin_amdgcn_readlane(vidx, r); // SGPR idx
                buf[j] = *(const float2*)(tab + (size_t)row * D + lane * 2);
            }
        };
        auto FMA = [&](float2 (&buf)[8], int g) {
#pragma unroll
            for (int j = 0; j < 8; ++j) {
                const int r = (g << 3) + j;
                const float w = readlane_f(vw, r);               // SGPR weight
                acc.x = fmaf(buf[j].x, w, acc.x);
                acc.y = fmaf(buf[j].y, w, acc.y);
            }
        };

        LOAD(bufA, 0);
        int g = 0;
        for (; g + 2 <= ngrp; g += 2) {
            LOAD(bufB, g + 1);      // issue next 8 rows BEFORE waiting on A
            FMA(bufA, g);           // vmcnt(8): only A's rows drained
            if (g + 2 < ngrp) LOAD(bufA, g + 2);
            FMA(bufB, g + 1);
        }
        if (g < ngrp) FMA(bufA, g); // odd tail group
    }

    // Full row per wave: 512B contiguous store, no cross-lane reduce needed.
    *(float2*)(out + (size_t)b * (T * D) + t * D + lane * 2) = acc;
}

extern "C" void kernel_launch(void* const* d_in, const int* in_sizes, int n_in,
                              void* d_out, int out_size, void* d_ws, size_t ws_size,
                              hipStream_t stream) {
    const float* tables  = (const float*)d_in[0];
    const int*   values  = (const int*)d_in[1];
    const int*   offsets = (const int*)d_in[2];
    const float* psw     = (const float*)d_in[3];
    float*       out     = (float*)d_out;

    dim3 grid((T * B) / 4);   // 4 bags (waves) per 256-thread block
    dim3 block(256);
    grouped_ebag_kernel<<<grid, block, 0, stream>>>(tables, values, offsets, psw, out);
}